// Round 1
// baseline (4306.716 us; speedup 1.0000x reference)
//
#include <hip/hip_runtime.h>
#include <math.h>

#define B_  4
#define S_  2048
#define D_  256
#define H_  8
#define HD_ 32
#define INV_SCALE 0.17677669529663687f   // 1/sqrt(32)

// ---------------- reductions ----------------
__device__ __forceinline__ float wave_sum(float v) {
#pragma unroll
    for (int o = 32; o > 0; o >>= 1) v += __shfl_down(v, o, 64);
    return v;
}
__device__ __forceinline__ float wave_max(float v) {
#pragma unroll
    for (int o = 32; o > 0; o >>= 1) v = fmaxf(v, __shfl_down(v, o, 64));
    return v;
}

// 256-thread block sum using 4-entry scratch
__device__ __forceinline__ float block_sum256(float v, float* scr) {
    v = wave_sum(v);
    int lane = threadIdx.x & 63, wid = threadIdx.x >> 6;
    if (lane == 0) scr[wid] = v;
    __syncthreads();
    float r = scr[0] + scr[1] + scr[2] + scr[3];
    __syncthreads();
    return r;
}

// ---------------- LayerNorm ----------------
// one block per token (B*S blocks), 256 threads = D elements
__global__ __launch_bounds__(256)
void ln_kernel(const float* __restrict__ x, const float* __restrict__ g,
               const float* __restrict__ b, float* __restrict__ xn) {
    __shared__ float scr[4];
    int t = threadIdx.x;
    size_t base = (size_t)blockIdx.x * D_;
    float v  = x[base + t];
    float mu = block_sum256(v, scr) * (1.0f / D_);
    float d  = v - mu;
    float var = block_sum256(d * d, scr) * (1.0f / D_);
    float rstd = rsqrtf(var + 1e-5f);
    xn[base + t] = d * rstd * g[t] + b[t];
}

// ---------------- dual-A GEMM with fused epilogue ----------------
// C[row,col] = sum_k A1[row,k]*W1[col,k] (+ A2[row,k]*W2[col,k]) (+ bias[col])
// epi: 0 none, 1 relu, 2 sigmoid, 3 sigmoid*resid, 4 tanh + GRU combine
__global__ __launch_bounds__(256)
void gemm_dual(const float* __restrict__ A1, const float* __restrict__ W1,
               const float* __restrict__ A2, const float* __restrict__ W2,
               const float* __restrict__ bias, const float* __restrict__ zbuf,
               const float* __restrict__ resid, float* __restrict__ out,
               int M, int N, int K, int epi) {
    __shared__ __align__(16) float As[16][64];
    __shared__ __align__(16) float Ws[16][64];
    int tid = threadIdx.x;
    int m0 = blockIdx.y * 64, n0 = blockIdx.x * 64;
    int lr = tid >> 2;           // 0..63: tile row for loads
    int lk = (tid & 3) * 4;      // 0,4,8,12: k offset for loads
    int tm = (tid >> 4) * 4;     // micro-tile row base
    int tn = (tid & 15) * 4;     // micro-tile col base

    float acc[4][4] = {};
    for (int pass = 0; pass < 2; ++pass) {
        const float* A = pass ? A2 : A1;
        const float* W = pass ? W2 : W1;
        if (A == nullptr) continue;
        for (int k0 = 0; k0 < K; k0 += 16) {
            float4 av = *(const float4*)&A[(size_t)(m0 + lr) * K + k0 + lk];
            float4 wv = *(const float4*)&W[(size_t)(n0 + lr) * K + k0 + lk];
            __syncthreads();   // protect previous iteration's LDS reads
            As[lk + 0][lr] = av.x; As[lk + 1][lr] = av.y;
            As[lk + 2][lr] = av.z; As[lk + 3][lr] = av.w;
            Ws[lk + 0][lr] = wv.x; Ws[lk + 1][lr] = wv.y;
            Ws[lk + 2][lr] = wv.z; Ws[lk + 3][lr] = wv.w;
            __syncthreads();
#pragma unroll
            for (int k = 0; k < 16; ++k) {
                float4 a = *(const float4*)&As[k][tm];
                float4 w = *(const float4*)&Ws[k][tn];
                acc[0][0] += a.x * w.x; acc[0][1] += a.x * w.y;
                acc[0][2] += a.x * w.z; acc[0][3] += a.x * w.w;
                acc[1][0] += a.y * w.x; acc[1][1] += a.y * w.y;
                acc[1][2] += a.y * w.z; acc[1][3] += a.y * w.w;
                acc[2][0] += a.z * w.x; acc[2][1] += a.z * w.y;
                acc[2][2] += a.z * w.z; acc[2][3] += a.z * w.w;
                acc[3][0] += a.w * w.x; acc[3][1] += a.w * w.y;
                acc[3][2] += a.w * w.z; acc[3][3] += a.w * w.w;
            }
        }
    }

#pragma unroll
    for (int i = 0; i < 4; ++i) {
        int row = m0 + tm + i;
        float vals[4];
#pragma unroll
        for (int j = 0; j < 4; ++j) {
            int col = n0 + tn + j;
            float v = acc[i][j] + (bias ? bias[col] : 0.0f);
            if (epi == 1) {
                v = fmaxf(v, 0.0f);
            } else if (epi == 2) {
                v = 1.0f / (1.0f + __expf(-v));
            } else if (epi == 3) {
                v = (1.0f / (1.0f + __expf(-v))) * resid[(size_t)row * N + col];
            } else if (epi == 4) {
                float h = tanhf(v);
                size_t idx = (size_t)row * N + col;
                float z = zbuf[idx], rs = resid[idx];
                v = (1.0f - z) * rs + z * h;
            }
            vals[j] = v;
        }
        *(float4*)&out[(size_t)row * N + n0 + tn] =
            make_float4(vals[0], vals[1], vals[2], vals[3]);
    }
}

// ---------------- attention ----------------
// grid (S, B*H); block 256. One block = one (head-batch n, query qi).
// qkv layout: [B, S, 768], head h occupies cols [h*96, h*96+96): q|k|v of 32.
// Writes directly in the reference's scrambled layout:
// out[b'=n%4][qi][(n>>2)*32 + d]
__global__ __launch_bounds__(256)
void attn_kernel(const float* __restrict__ qkv, const int* __restrict__ adj,
                 float* __restrict__ attn_out) {
    __shared__ float p_sh[S_];
    __shared__ __align__(16) float q_sh[HD_];
    __shared__ float red[8][33];
    __shared__ float scr[4];

    int tid = threadIdx.x;
    int qi = blockIdx.x, n = blockIdx.y;
    int b = n >> 3, h = n & 7;
    int bp = n & 3, hp = n >> 2;

    const float* qrow = qkv + ((size_t)(b * S_ + qi)) * 768 + h * 96;
    if (tid < 8) ((float4*)q_sh)[tid] = ((const float4*)qrow)[tid];
    __syncthreads();

    float4 qv[8];
#pragma unroll
    for (int j = 0; j < 8; ++j) qv[j] = ((float4*)q_sh)[j];

    // scores for 8 keys per thread
    float sc[8];
#pragma unroll
    for (int jj = 0; jj < 8; ++jj) {
        int ki = jj * 256 + tid;
        const float* krow = qkv + ((size_t)(b * S_ + ki)) * 768 + h * 96 + 32;
        float dot = 0.0f;
#pragma unroll
        for (int j = 0; j < 8; ++j) {
            float4 kv = ((const float4*)krow)[j];
            dot += qv[j].x * kv.x + qv[j].y * kv.y + qv[j].z * kv.z + qv[j].w * kv.w;
        }
        int a = adj[((size_t)b * S_ + qi) * S_ + ki];
        sc[jj] = (a == 0) ? -INFINITY : dot * INV_SCALE;
    }

    // block max
    float mx = sc[0];
#pragma unroll
    for (int jj = 1; jj < 8; ++jj) mx = fmaxf(mx, sc[jj]);
    mx = wave_max(mx);
    int lane = tid & 63, wid = tid >> 6;
    if (lane == 0) scr[wid] = mx;
    __syncthreads();
    mx = fmaxf(fmaxf(scr[0], scr[1]), fmaxf(scr[2], scr[3]));
    __syncthreads();

    // exp + sum; p -> LDS
    float ls = 0.0f;
#pragma unroll
    for (int jj = 0; jj < 8; ++jj) {
        float p = __expf(sc[jj] - mx);   // exp(-inf)=0 handles the mask
        p_sh[jj * 256 + tid] = p;
        ls += p;
    }
    ls = wave_sum(ls);
    if (lane == 0) scr[wid] = ls;
    __syncthreads();                     // also orders p_sh writes
    float stot = scr[0] + scr[1] + scr[2] + scr[3];

    // P·V: 8 chunks of 256 keys × 32 dims
    int d = tid & 31, chunk = tid >> 5;
    const float* vbase = qkv + (size_t)b * S_ * 768 + h * 96 + 64 + d;
    float acc = 0.0f;
    int k0 = chunk * 256;
#pragma unroll 4
    for (int kk = 0; kk < 256; ++kk) {
        int ki = k0 + kk;
        acc += p_sh[ki] * vbase[(size_t)ki * 768];
    }
    red[chunk][d] = acc;
    __syncthreads();
    if (tid < 32) {
        float tot = 0.0f;
#pragma unroll
        for (int c = 0; c < 8; ++c) tot += red[c][tid];
        attn_out[((size_t)(bp * S_ + qi)) * D_ + hp * HD_ + tid] = tot / stot;
    }
}

// ---------------- launch ----------------
extern "C" void kernel_launch(void* const* d_in, const int* in_sizes, int n_in,
                              void* d_out, int out_size, void* d_ws, size_t ws_size,
                              hipStream_t stream) {
    const float* x     = (const float*)d_in[0];
    const int*   adj   = (const int*)d_in[1];
    const float* w_qkv = (const float*)d_in[2];
    const float* b_qkv = (const float*)d_in[3];
    const float* ln_g  = (const float*)d_in[4];
    const float* ln_b  = (const float*)d_in[5];
    const float* w_fc  = (const float*)d_in[6];
    const float* b_fc  = (const float*)d_in[7];
    const float* w_z   = (const float*)d_in[8];
    const float* b_z   = (const float*)d_in[9];
    const float* u_z   = (const float*)d_in[10];
    const float* w_r   = (const float*)d_in[11];
    const float* u_r   = (const float*)d_in[12];
    const float* w_g   = (const float*)d_in[13];
    const float* u_g   = (const float*)d_in[14];
    float* out = (float*)d_out;
    float* ws  = (float*)d_ws;

    const size_t TOK = (size_t)B_ * S_;          // 8192
    float* xn     = ws;                          // 8192*256
    float* qkv    = ws + TOK * D_;               // 8192*768
    float* attn_o = qkv + TOK * 3 * D_;          // 8192*256
    float* y      = attn_o + TOK * D_;           // 8192*256
    float* z      = y + TOK * D_;                // 8192*256
    float* t      = z + TOK * D_;                // 8192*256

    ln_kernel<<<TOK, 256, 0, stream>>>(x, ln_g, ln_b, xn);

    dim3 gqkv(3 * D_ / 64, TOK / 64);
    gemm_dual<<<gqkv, 256, 0, stream>>>(xn, w_qkv, nullptr, nullptr, b_qkv,
                                        nullptr, nullptr, qkv,
                                        (int)TOK, 3 * D_, D_, 0);

    attn_kernel<<<dim3(S_, B_ * H_), 256, 0, stream>>>(qkv, adj, attn_o);

    dim3 g256(D_ / 64, TOK / 64);
    gemm_dual<<<g256, 256, 0, stream>>>(attn_o, w_fc, nullptr, nullptr, b_fc,
                                        nullptr, nullptr, y,
                                        (int)TOK, D_, D_, 1);
    gemm_dual<<<g256, 256, 0, stream>>>(y, w_z, x, u_z, b_z,
                                        nullptr, nullptr, z,
                                        (int)TOK, D_, D_, 2);
    gemm_dual<<<g256, 256, 0, stream>>>(y, w_r, x, u_r, nullptr,
                                        nullptr, x, t,
                                        (int)TOK, D_, D_, 3);
    gemm_dual<<<g256, 256, 0, stream>>>(y, w_g, t, u_g, nullptr,
                                        z, x, out,
                                        (int)TOK, D_, D_, 4);
}

// Round 2
// 612.439 us; speedup vs baseline: 7.0321x; 7.0321x over previous
//
#include <hip/hip_runtime.h>
#include <math.h>

#define B_  4
#define S_  2048
#define D_  256
#define H_  8
#define HD_ 32
#define INV_SCALE 0.17677669529663687f   // 1/sqrt(32)

// ---------------- reductions ----------------
__device__ __forceinline__ float wave_sum(float v) {
#pragma unroll
    for (int o = 32; o > 0; o >>= 1) v += __shfl_down(v, o, 64);
    return v;
}

// 256-thread block sum using 4-entry scratch
__device__ __forceinline__ float block_sum256(float v, float* scr) {
    v = wave_sum(v);
    int lane = threadIdx.x & 63, wid = threadIdx.x >> 6;
    if (lane == 0) scr[wid] = v;
    __syncthreads();
    float r = scr[0] + scr[1] + scr[2] + scr[3];
    __syncthreads();
    return r;
}

// ---------------- LayerNorm ----------------
__global__ __launch_bounds__(256)
void ln_kernel(const float* __restrict__ x, const float* __restrict__ g,
               const float* __restrict__ b, float* __restrict__ xn) {
    __shared__ float scr[4];
    int t = threadIdx.x;
    size_t base = (size_t)blockIdx.x * D_;
    float v  = x[base + t];
    float mu = block_sum256(v, scr) * (1.0f / D_);
    float d  = v - mu;
    float var = block_sum256(d * d, scr) * (1.0f / D_);
    float rstd = rsqrtf(var + 1e-5f);
    xn[base + t] = d * rstd * g[t] + b[t];
}

// ---------------- dual-A GEMM with fused epilogue ----------------
__global__ __launch_bounds__(256)
void gemm_dual(const float* __restrict__ A1, const float* __restrict__ W1,
               const float* __restrict__ A2, const float* __restrict__ W2,
               const float* __restrict__ bias, const float* __restrict__ zbuf,
               const float* __restrict__ resid, float* __restrict__ out,
               int M, int N, int K, int epi) {
    __shared__ __align__(16) float As[16][64];
    __shared__ __align__(16) float Ws[16][64];
    int tid = threadIdx.x;
    int m0 = blockIdx.y * 64, n0 = blockIdx.x * 64;
    int lr = tid >> 2;
    int lk = (tid & 3) * 4;
    int tm = (tid >> 4) * 4;
    int tn = (tid & 15) * 4;

    float acc[4][4] = {};
    for (int pass = 0; pass < 2; ++pass) {
        const float* A = pass ? A2 : A1;
        const float* W = pass ? W2 : W1;
        if (A == nullptr) continue;
        for (int k0 = 0; k0 < K; k0 += 16) {
            float4 av = *(const float4*)&A[(size_t)(m0 + lr) * K + k0 + lk];
            float4 wv = *(const float4*)&W[(size_t)(n0 + lr) * K + k0 + lk];
            __syncthreads();
            As[lk + 0][lr] = av.x; As[lk + 1][lr] = av.y;
            As[lk + 2][lr] = av.z; As[lk + 3][lr] = av.w;
            Ws[lk + 0][lr] = wv.x; Ws[lk + 1][lr] = wv.y;
            Ws[lk + 2][lr] = wv.z; Ws[lk + 3][lr] = wv.w;
            __syncthreads();
#pragma unroll
            for (int k = 0; k < 16; ++k) {
                float4 a = *(const float4*)&As[k][tm];
                float4 w = *(const float4*)&Ws[k][tn];
                acc[0][0] += a.x * w.x; acc[0][1] += a.x * w.y;
                acc[0][2] += a.x * w.z; acc[0][3] += a.x * w.w;
                acc[1][0] += a.y * w.x; acc[1][1] += a.y * w.y;
                acc[1][2] += a.y * w.z; acc[1][3] += a.y * w.w;
                acc[2][0] += a.z * w.x; acc[2][1] += a.z * w.y;
                acc[2][2] += a.z * w.z; acc[2][3] += a.z * w.w;
                acc[3][0] += a.w * w.x; acc[3][1] += a.w * w.y;
                acc[3][2] += a.w * w.z; acc[3][3] += a.w * w.w;
            }
        }
    }

#pragma unroll
    for (int i = 0; i < 4; ++i) {
        int row = m0 + tm + i;
        float vals[4];
#pragma unroll
        for (int j = 0; j < 4; ++j) {
            int col = n0 + tn + j;
            float v = acc[i][j] + (bias ? bias[col] : 0.0f);
            if (epi == 1) {
                v = fmaxf(v, 0.0f);
            } else if (epi == 2) {
                v = 1.0f / (1.0f + __expf(-v));
            } else if (epi == 3) {
                v = (1.0f / (1.0f + __expf(-v))) * resid[(size_t)row * N + col];
            } else if (epi == 4) {
                float h = tanhf(v);
                size_t idx = (size_t)row * N + col;
                float z = zbuf[idx], rs = resid[idx];
                v = (1.0f - z) * rs + z * h;
            }
            vals[j] = v;
        }
        *(float4*)&out[(size_t)row * N + n0 + tn] =
            make_float4(vals[0], vals[1], vals[2], vals[3]);
    }
}

// ---------------- flash-style attention ----------------
// grid (S/64, B*H), block 256. One block = (head n, 64-query tile).
// No max-subtraction softmax: scores are O(3.5) max, exp() safe in fp32;
// masked entries contribute exactly 0 — identical to softmax(where(adj,s,-inf)).
// Writes reference's scrambled layout: out[n%4][q][(n>>2)*32 + d].
__global__ __launch_bounds__(256)
void attn_kernel(const float* __restrict__ qkv, const int* __restrict__ adj,
                 float* __restrict__ attn_out) {
    __shared__ __align__(16) float Qs[32][68];   // [kdim][query], padded
    __shared__ __align__(16) float Ks[32][68];   // [kdim][key], padded
    __shared__ __align__(16) float Vs[64][32];   // [key][d]
    __shared__ __align__(16) float Ps[64][68];   // [key][query], padded; reused as O-scratch
    __shared__ float l_sh[64];

    int tid = threadIdx.x;
    int q0 = blockIdx.x * 64;
    int n  = blockIdx.y;
    int b = n >> 3, h = n & 7;
    int bp = n & 3, hp = n >> 2;

    // S-compute mapping: 4 queries x 4 keys per thread
    int ti = tid >> 4;      // 0..15 query group
    int tj = tid & 15;      // 0..15 key group
    // PV mapping: 4 queries x 4 dims per thread, split over 2 key halves
    int qi4 = tid & 15;
    int d4  = (tid >> 4) & 7;
    int kh  = tid >> 7;     // 0/1

    const float* qkv_b = qkv + (size_t)b * S_ * 768 + h * 96;

    // stage Q tile (transposed into Qs[kd][q]); visibility covered by the
    // second __syncthreads inside the first tile iteration.
#pragma unroll
    for (int rep = 0; rep < 2; ++rep) {
        int idx = rep * 256 + tid;
        int qq = idx >> 3, f4 = (idx & 7) * 4;
        float4 v = *(const float4*)(qkv_b + (size_t)(q0 + qq) * 768 + f4);
        Qs[f4 + 0][qq] = v.x; Qs[f4 + 1][qq] = v.y;
        Qs[f4 + 2][qq] = v.z; Qs[f4 + 3][qq] = v.w;
    }

    float o[4][4] = {};
    float l[4] = {0.f, 0.f, 0.f, 0.f};

    for (int k0 = 0; k0 < S_; k0 += 64) {
        // prefetch K/V/adj into registers (global, overlaps prev tile's tail)
        float4 kreg[2], vreg[2];
        int key_[2], kf4_[2];
#pragma unroll
        for (int rep = 0; rep < 2; ++rep) {
            int idx = rep * 256 + tid;
            int key = idx >> 3, f4 = (idx & 7) * 4;
            key_[rep] = key; kf4_[rep] = f4;
            kreg[rep] = *(const float4*)(qkv_b + (size_t)(k0 + key) * 768 + 32 + f4);
            vreg[rep] = *(const float4*)(qkv_b + (size_t)(k0 + key) * 768 + 64 + f4);
        }
        int4 am[4];
#pragma unroll
        for (int i = 0; i < 4; ++i)
            am[i] = *(const int4*)(adj + ((size_t)b * S_ + (q0 + ti * 4 + i)) * S_ + k0 + tj * 4);

        __syncthreads();   // previous tile's Ks/Vs/Ps reads complete
#pragma unroll
        for (int rep = 0; rep < 2; ++rep) {
            int key = key_[rep], f4 = kf4_[rep];
            Ks[f4 + 0][key] = kreg[rep].x; Ks[f4 + 1][key] = kreg[rep].y;
            Ks[f4 + 2][key] = kreg[rep].z; Ks[f4 + 3][key] = kreg[rep].w;
            *(float4*)&Vs[key][f4] = vreg[rep];
        }
        __syncthreads();

        // scores: S[4q][4k] over 32 dims
        float sc[4][4] = {};
#pragma unroll 8
        for (int kd = 0; kd < 32; ++kd) {
            float4 a  = *(const float4*)&Qs[kd][ti * 4];
            float4 bb = *(const float4*)&Ks[kd][tj * 4];
            sc[0][0] += a.x * bb.x; sc[0][1] += a.x * bb.y;
            sc[0][2] += a.x * bb.z; sc[0][3] += a.x * bb.w;
            sc[1][0] += a.y * bb.x; sc[1][1] += a.y * bb.y;
            sc[1][2] += a.y * bb.z; sc[1][3] += a.y * bb.w;
            sc[2][0] += a.z * bb.x; sc[2][1] += a.z * bb.y;
            sc[2][2] += a.z * bb.z; sc[2][3] += a.z * bb.w;
            sc[3][0] += a.w * bb.x; sc[3][1] += a.w * bb.y;
            sc[3][2] += a.w * bb.z; sc[3][3] += a.w * bb.w;
        }

        // mask + exp -> P, accumulate row sums, store P transposed
#pragma unroll
        for (int j = 0; j < 4; ++j) {
            float p[4];
#pragma unroll
            for (int i = 0; i < 4; ++i) {
                const int* ai = &am[i].x;
                p[i] = (ai[j] != 0) ? __expf(sc[i][j] * INV_SCALE) : 0.0f;
                l[i] += p[i];
            }
            *(float4*)&Ps[tj * 4 + j][ti * 4] = make_float4(p[0], p[1], p[2], p[3]);
        }
        __syncthreads();

        // PV: O[4q][4d] += P[q][key] * V[key][d] over this thread's key half
#pragma unroll 8
        for (int kk = 0; kk < 32; ++kk) {
            int key = kh * 32 + kk;
            float4 pq = *(const float4*)&Ps[key][qi4 * 4];
            float4 vv = *(const float4*)&Vs[key][d4 * 4];
            o[0][0] += pq.x * vv.x; o[0][1] += pq.x * vv.y;
            o[0][2] += pq.x * vv.z; o[0][3] += pq.x * vv.w;
            o[1][0] += pq.y * vv.x; o[1][1] += pq.y * vv.y;
            o[1][2] += pq.y * vv.z; o[1][3] += pq.y * vv.w;
            o[2][0] += pq.z * vv.x; o[2][1] += pq.z * vv.y;
            o[2][2] += pq.z * vv.z; o[2][3] += pq.z * vv.w;
            o[3][0] += pq.w * vv.x; o[3][1] += pq.w * vv.y;
            o[3][2] += pq.w * vv.z; o[3][3] += pq.w * vv.w;
        }
    }

    // reduce l across the 16 key-group threads (lanes tj 0..15 share a row group)
#pragma unroll
    for (int i = 0; i < 4; ++i) {
        float s = l[i];
        s += __shfl_xor(s, 1, 64);
        s += __shfl_xor(s, 2, 64);
        s += __shfl_xor(s, 4, 64);
        s += __shfl_xor(s, 8, 64);
        if (tj == 0) l_sh[ti * 4 + i] = s;
    }
    __syncthreads();   // also: all Ps reads done -> reuse as scratch

    float* scr = &Ps[0][0];    // 128*16 floats needed, 64*68 available
    if (kh == 1) {
#pragma unroll
        for (int e = 0; e < 4; ++e)
            *(float4*)&scr[(size_t)(tid - 128) * 16 + e * 4] =
                make_float4(o[e][0], o[e][1], o[e][2], o[e][3]);
    }
    __syncthreads();
    if (kh == 0) {
#pragma unroll
        for (int e = 0; e < 4; ++e) {
            float4 add = *(const float4*)&scr[(size_t)tid * 16 + e * 4];
            o[e][0] += add.x; o[e][1] += add.y; o[e][2] += add.z; o[e][3] += add.w;
        }
#pragma unroll
        for (int i = 0; i < 4; ++i) {
            int q = qi4 * 4 + i;
            float linv = 1.0f / l_sh[q];
            float4 w = make_float4(o[i][0] * linv, o[i][1] * linv,
                                   o[i][2] * linv, o[i][3] * linv);
            *(float4*)&attn_out[((size_t)(bp * S_ + q0 + q)) * D_ + hp * HD_ + d4 * 4] = w;
        }
    }
}

// ---------------- launch ----------------
extern "C" void kernel_launch(void* const* d_in, const int* in_sizes, int n_in,
                              void* d_out, int out_size, void* d_ws, size_t ws_size,
                              hipStream_t stream) {
    const float* x     = (const float*)d_in[0];
    const int*   adj   = (const int*)d_in[1];
    const float* w_qkv = (const float*)d_in[2];
    const float* b_qkv = (const float*)d_in[3];
    const float* ln_g  = (const float*)d_in[4];
    const float* ln_b  = (const float*)d_in[5];
    const float* w_fc  = (const float*)d_in[6];
    const float* b_fc  = (const float*)d_in[7];
    const float* w_z   = (const float*)d_in[8];
    const float* b_z   = (const float*)d_in[9];
    const float* u_z   = (const float*)d_in[10];
    const float* w_r   = (const float*)d_in[11];
    const float* u_r   = (const float*)d_in[12];
    const float* w_g   = (const float*)d_in[13];
    const float* u_g   = (const float*)d_in[14];
    float* out = (float*)d_out;
    float* ws  = (float*)d_ws;

    const size_t TOK = (size_t)B_ * S_;          // 8192
    float* xn     = ws;
    float* qkv    = ws + TOK * D_;
    float* attn_o = qkv + TOK * 3 * D_;
    float* y      = attn_o + TOK * D_;
    float* z      = y + TOK * D_;
    float* t      = z + TOK * D_;

    ln_kernel<<<TOK, 256, 0, stream>>>(x, ln_g, ln_b, xn);

    dim3 gqkv(3 * D_ / 64, TOK / 64);
    gemm_dual<<<gqkv, 256, 0, stream>>>(xn, w_qkv, nullptr, nullptr, b_qkv,
                                        nullptr, nullptr, qkv,
                                        (int)TOK, 3 * D_, D_, 0);

    attn_kernel<<<dim3(S_ / 64, B_ * H_), 256, 0, stream>>>(qkv, adj, attn_o);

    dim3 g256(D_ / 64, TOK / 64);
    gemm_dual<<<g256, 256, 0, stream>>>(attn_o, w_fc, nullptr, nullptr, b_fc,
                                        nullptr, nullptr, y,
                                        (int)TOK, D_, D_, 1);
    gemm_dual<<<g256, 256, 0, stream>>>(y, w_z, x, u_z, b_z,
                                        nullptr, nullptr, z,
                                        (int)TOK, D_, D_, 2);
    gemm_dual<<<g256, 256, 0, stream>>>(y, w_r, x, u_r, nullptr,
                                        nullptr, x, t,
                                        (int)TOK, D_, D_, 3);
    gemm_dual<<<g256, 256, 0, stream>>>(y, w_g, t, u_g, nullptr,
                                        z, x, out,
                                        (int)TOK, D_, D_, 4);
}

// Round 3
// 282.184 us; speedup vs baseline: 15.2621x; 2.1704x over previous
//
#include <hip/hip_runtime.h>
#include <math.h>

#define B_  4
#define S_  2048
#define D_  256
#define H_  8
#define HD_ 32
#define INV_SCALE 0.17677669529663687f   // 1/sqrt(32)

typedef short  bf16x8 __attribute__((ext_vector_type(8)));
typedef float  f32x4  __attribute__((ext_vector_type(4)));
typedef unsigned short ushort_t;
typedef unsigned int   uint_t;

__device__ __forceinline__ ushort_t f2b(float f) {
    union { float f; unsigned u; } v; v.f = f;
    unsigned r = (v.u + 0x7FFFu + ((v.u >> 16) & 1u)) >> 16;
    return (ushort_t)r;
}

// ---------------- reductions ----------------
__device__ __forceinline__ float wave_sum(float v) {
#pragma unroll
    for (int o = 32; o > 0; o >>= 1) v += __shfl_down(v, o, 64);
    return v;
}
__device__ __forceinline__ float block_sum256(float v, float* scr) {
    v = wave_sum(v);
    int lane = threadIdx.x & 63, wid = threadIdx.x >> 6;
    if (lane == 0) scr[wid] = v;
    __syncthreads();
    float r = scr[0] + scr[1] + scr[2] + scr[3];
    __syncthreads();
    return r;
}

// ---------------- LayerNorm (+ bf16 copies of xn and x) ----------------
__global__ __launch_bounds__(256)
void ln_kernel(const float* __restrict__ x, const float* __restrict__ g,
               const float* __restrict__ b, ushort_t* __restrict__ xn_b,
               ushort_t* __restrict__ x_b) {
    __shared__ float scr[4];
    int t = threadIdx.x;
    size_t base = (size_t)blockIdx.x * D_;
    float v  = x[base + t];
    float mu = block_sum256(v, scr) * (1.0f / D_);
    float d  = v - mu;
    float var = block_sum256(d * d, scr) * (1.0f / D_);
    float rstd = rsqrtf(var + 1e-5f);
    xn_b[base + t] = f2b(d * rstd * g[t] + b[t]);
    x_b[base + t]  = f2b(v);
}

// ---------------- weight convert fp32 -> bf16 (8 segments) ----------------
#define WQ_SZ 196608   // 768*256
#define WS_SZ 65536    // 256*256
__global__ __launch_bounds__(256)
void wcvt_kernel(const float* __restrict__ w0, const float* __restrict__ w1,
                 const float* __restrict__ w2, const float* __restrict__ w3,
                 const float* __restrict__ w4, const float* __restrict__ w5,
                 const float* __restrict__ w6, const float* __restrict__ w7,
                 ushort_t* __restrict__ out) {
    int idx = blockIdx.x * 256 + threadIdx.x;
    if (idx >= WQ_SZ + 7 * WS_SZ) return;
    const float* src; int off;
    if (idx < WQ_SZ) { src = w0; off = idx; }
    else {
        int j = idx - WQ_SZ, seg = j >> 16; off = j & (WS_SZ - 1);
        src = (seg == 0) ? w1 : (seg == 1) ? w2 : (seg == 2) ? w3 :
              (seg == 3) ? w4 : (seg == 4) ? w5 : (seg == 5) ? w6 : w7;
    }
    out[idx] = f2b(src[off]);
}

// ---------------- adj -> bitmask ----------------
__global__ __launch_bounds__(256)
void adjbits_kernel(const int* __restrict__ adj, uint_t* __restrict__ bits) {
    size_t i = (size_t)blockIdx.x * 256 + threadIdx.x;
    unsigned long long m = __ballot(adj[i] != 0);
    int lane = threadIdx.x & 63;
    size_t wbase = ((size_t)blockIdx.x * 256 + (threadIdx.x & ~63)) >> 5;
    if (lane == 0)  bits[wbase]     = (uint_t)m;
    if (lane == 32) bits[wbase + 1] = (uint_t)(m >> 32);
}

// ---------------- bf16 MFMA GEMM, dual-A, fused epilogue ----------------
// C[row,col] = sum_k A1[row,k]*W1[col,k] (+A2*W2) (+bias)
// epi: 0 none, 1 relu, 2 sigmoid, 3 sigmoid*resid, 4 tanh+GRU combine
__global__ __launch_bounds__(256)
void gemm_bf16(const ushort_t* __restrict__ A1, const ushort_t* __restrict__ W1,
               const ushort_t* __restrict__ A2, const ushort_t* __restrict__ W2,
               const float* __restrict__ bias, const float* __restrict__ zbuf,
               const float* __restrict__ resid, float* __restrict__ outf,
               ushort_t* __restrict__ outb, int M, int N, int K, int epi) {
    __shared__ ushort_t As[64][40];
    __shared__ ushort_t Ws[64][40];
    int tid = threadIdx.x;
    int wave = tid >> 6, lane = tid & 63, l = lane & 15, quad = lane >> 4;
    int wm = wave >> 1, wn = wave & 1;
    int m0 = blockIdx.y * 64, n0 = blockIdx.x * 64;
    int srow = tid >> 2, skp = tid & 3;

    const ushort_t* Aps[2] = {A1, A2};
    const ushort_t* Wps[2] = {W1, W2};
    int ksteps = K >> 5;
    int nsteps = (A2 ? 2 : 1) * ksteps;

    f32x4 acc[2][2];
#pragma unroll
    for (int i = 0; i < 2; ++i)
#pragma unroll
        for (int j = 0; j < 2; ++j) acc[i][j] = (f32x4){0.f, 0.f, 0.f, 0.f};

    uint4 av = *(const uint4*)(Aps[0] + (size_t)(m0 + srow) * K + skp * 8);
    uint4 wv = *(const uint4*)(Wps[0] + (size_t)(n0 + srow) * K + skp * 8);

    for (int s = 0; s < nsteps; ++s) {
        uint4 ac = av, wc = wv;
        if (s + 1 < nsteps) {
            int s1 = s + 1;
            int p  = (s1 >= ksteps) ? 1 : 0;
            int kk = (s1 - p * ksteps) * 32;
            av = *(const uint4*)(Aps[p] + (size_t)(m0 + srow) * K + kk + skp * 8);
            wv = *(const uint4*)(Wps[p] + (size_t)(n0 + srow) * K + kk + skp * 8);
        }
        __syncthreads();
        *(uint4*)&As[srow][skp * 8] = ac;
        *(uint4*)&Ws[srow][skp * 8] = wc;
        __syncthreads();

        bf16x8 af[2], wf[2];
#pragma unroll
        for (int mt = 0; mt < 2; ++mt)
            af[mt] = *(const bf16x8*)&As[wm * 32 + mt * 16 + l][quad * 8];
#pragma unroll
        for (int nt = 0; nt < 2; ++nt)
            wf[nt] = *(const bf16x8*)&Ws[wn * 32 + nt * 16 + l][quad * 8];
#pragma unroll
        for (int mt = 0; mt < 2; ++mt)
#pragma unroll
            for (int nt = 0; nt < 2; ++nt)
                acc[mt][nt] = __builtin_amdgcn_mfma_f32_16x16x32_bf16(
                    af[mt], wf[nt], acc[mt][nt], 0, 0, 0);
    }

#pragma unroll
    for (int mt = 0; mt < 2; ++mt)
#pragma unroll
        for (int nt = 0; nt < 2; ++nt) {
            int col = n0 + wn * 32 + nt * 16 + l;
            float bv = bias ? bias[col] : 0.0f;
#pragma unroll
            for (int r = 0; r < 4; ++r) {
                int row = m0 + wm * 32 + mt * 16 + quad * 4 + r;
                float v = acc[mt][nt][r] + bv;
                size_t idx = (size_t)row * N + col;
                if (epi == 1) {
                    v = fmaxf(v, 0.0f);
                } else if (epi == 2) {
                    v = 1.0f / (1.0f + __expf(-v));
                } else if (epi == 3) {
                    v = (1.0f / (1.0f + __expf(-v))) * resid[idx];
                } else if (epi == 4) {
                    float h = tanhf(v);
                    float z = zbuf[idx], rs = resid[idx];
                    v = (1.0f - z) * rs + z * h;
                }
                if (outf) outf[idx] = v;
                if (outb) outb[idx] = f2b(v);
            }
        }
}

// ---------------- MFMA flash attention ----------------
// grid (S/64, B*H), block 256 (4 waves; wave w owns queries q0+16w..+15).
// qkv_b: [B,S,768] bf16, head h at cols [h*96, h*96+96): q|k|v of 32.
// abits: [B*S][64] uint32 adjacency bitmask.
// Output (bf16) in reference scrambled layout: out[n%4][q][(n>>2)*32+d].
__global__ __launch_bounds__(256)
void attn_kernel(const ushort_t* __restrict__ qkvb, const uint_t* __restrict__ abits,
                 ushort_t* __restrict__ attn_b) {
    __shared__ ushort_t Ks[64][40];   // [key][d]
    __shared__ ushort_t Vt[32][72];   // [d][key]
    __shared__ ushort_t Ps[64][72];   // [q][key] (wave-private 16-row bands)
    __shared__ uint_t  ab_sh[64][2];
    __shared__ float   l_sh[64];

    int tid = threadIdx.x;
    int wave = tid >> 6, lane = tid & 63, l = lane & 15, quad = lane >> 4;
    int q0 = blockIdx.x * 64;
    int n  = blockIdx.y;
    int b = n >> 3, h = n & 7;
    int bp = n & 3, hp = n >> 2;

    const ushort_t* base = qkvb + (size_t)b * S_ * 768 + h * 96;

    // Q fragment: A[m=l][k=quad*8+j] for this wave's 16 queries
    bf16x8 qf = *(const bf16x8*)(base + (size_t)(q0 + wave * 16 + l) * 768 + quad * 8);

    f32x4 oacc[2];
    oacc[0] = (f32x4){0.f, 0.f, 0.f, 0.f};
    oacc[1] = (f32x4){0.f, 0.f, 0.f, 0.f};
    float lsum[4] = {0.f, 0.f, 0.f, 0.f};

    int skey = tid >> 2, spart = tid & 3;

    // prefetch tile 0
    uint4 kv = *(const uint4*)(base + (size_t)skey * 768 + 32 + spart * 8);
    uint4 vv = *(const uint4*)(base + (size_t)skey * 768 + 64 + spart * 8);
    uint_t aw = 0;
    if (tid < 128)
        aw = abits[((size_t)b * S_ + q0 + (tid >> 1)) * 64 + (tid & 1)];

    for (int k0 = 0; k0 < S_; k0 += 64) {
        uint4 kc = kv, vc = vv; uint_t ac = aw;
        if (k0 + 64 < S_) {
            kv = *(const uint4*)(base + (size_t)(k0 + 64 + skey) * 768 + 32 + spart * 8);
            vv = *(const uint4*)(base + (size_t)(k0 + 64 + skey) * 768 + 64 + spart * 8);
            if (tid < 128)
                aw = abits[((size_t)b * S_ + q0 + (tid >> 1)) * 64 + ((k0 + 64) >> 5) + (tid & 1)];
        }
        __syncthreads();
        *(uint4*)&Ks[skey][spart * 8] = kc;
        {
            const ushort_t* vs = (const ushort_t*)&vc;
#pragma unroll
            for (int i = 0; i < 8; ++i) Vt[spart * 8 + i][skey] = vs[i];
        }
        if (tid < 128) ab_sh[tid >> 1][tid & 1] = ac;
        __syncthreads();

        uint_t aw0[4], aw1[4];
#pragma unroll
        for (int r = 0; r < 4; ++r) {
            int q = wave * 16 + quad * 4 + r;
            aw0[r] = ab_sh[q][0];
            aw1[r] = ab_sh[q][1];
        }

        // QK^T: 4 key-groups of 16
#pragma unroll
        for (int t4 = 0; t4 < 4; ++t4) {
            bf16x8 kf = *(const bf16x8*)&Ks[t4 * 16 + l][quad * 8];
            f32x4 z = (f32x4){0.f, 0.f, 0.f, 0.f};
            f32x4 sc = __builtin_amdgcn_mfma_f32_16x16x32_bf16(qf, kf, z, 0, 0, 0);
#pragma unroll
            for (int r = 0; r < 4; ++r) {
                uint_t w = (t4 & 2) ? aw1[r] : aw0[r];
                int bit = (w >> ((t4 & 1) * 16 + l)) & 1;
                float p = bit ? __expf(sc[r] * INV_SCALE) : 0.0f;
                lsum[r] += p;
                Ps[wave * 16 + quad * 4 + r][t4 * 16 + l] = f2b(p);
            }
        }

        // PV^T: D[d][q] += V^T[d][k] * P^T[k][q]  (wave-private Ps rows; no barrier)
#pragma unroll
        for (int ks = 0; ks < 2; ++ks) {
            bf16x8 pf = *(const bf16x8*)&Ps[wave * 16 + l][ks * 32 + quad * 8];
#pragma unroll
            for (int mt = 0; mt < 2; ++mt) {
                bf16x8 vf = *(const bf16x8*)&Vt[mt * 16 + l][ks * 32 + quad * 8];
                oacc[mt] = __builtin_amdgcn_mfma_f32_16x16x32_bf16(vf, pf, oacc[mt], 0, 0, 0);
            }
        }
    }

    // row sums: reduce across the 16 l-lanes of each quad group
#pragma unroll
    for (int r = 0; r < 4; ++r) {
        float s = lsum[r];
        s += __shfl_xor(s, 1, 64);
        s += __shfl_xor(s, 2, 64);
        s += __shfl_xor(s, 4, 64);
        s += __shfl_xor(s, 8, 64);
        if (l == 0) l_sh[wave * 16 + quad * 4 + r] = s;
    }
    __syncthreads();
    float linv = 1.0f / l_sh[wave * 16 + l];

    size_t orow = ((size_t)(bp * S_ + q0 + wave * 16 + l)) * D_ + hp * HD_;
#pragma unroll
    for (int mt = 0; mt < 2; ++mt)
#pragma unroll
        for (int r = 0; r < 4; ++r)
            attn_b[orow + mt * 16 + quad * 4 + r] = f2b(oacc[mt][r] * linv);
}

// ---------------- launch ----------------
extern "C" void kernel_launch(void* const* d_in, const int* in_sizes, int n_in,
                              void* d_out, int out_size, void* d_ws, size_t ws_size,
                              hipStream_t stream) {
    const float* x     = (const float*)d_in[0];
    const int*   adj   = (const int*)d_in[1];
    const float* w_qkv = (const float*)d_in[2];
    const float* b_qkv = (const float*)d_in[3];
    const float* ln_g  = (const float*)d_in[4];
    const float* ln_b  = (const float*)d_in[5];
    const float* w_fc  = (const float*)d_in[6];
    const float* b_fc  = (const float*)d_in[7];
    const float* w_z   = (const float*)d_in[8];
    const float* b_z   = (const float*)d_in[9];
    const float* u_z   = (const float*)d_in[10];
    const float* w_r   = (const float*)d_in[11];
    const float* u_r   = (const float*)d_in[12];
    const float* w_g   = (const float*)d_in[13];
    const float* u_g   = (const float*)d_in[14];
    float* out = (float*)d_out;

    const size_t TOK = (size_t)B_ * S_;          // 8192
    ushort_t* xn_b   = (ushort_t*)d_ws;
    ushort_t* x_b    = xn_b + TOK * D_;
    ushort_t* qkv_b  = x_b + TOK * D_;
    ushort_t* attn_b = qkv_b + TOK * 3 * D_;
    ushort_t* y_b    = attn_b + TOK * D_;
    ushort_t* t_b    = y_b + TOK * D_;
    ushort_t* wb     = t_b + TOK * D_;           // 655360 bf16
    float*    z_f    = (float*)(wb + WQ_SZ + 7 * WS_SZ);
    uint_t*   bits   = (uint_t*)(z_f + TOK * D_);

    ushort_t* wq_b = wb;
    ushort_t* wfc_b = wb + WQ_SZ;
    ushort_t* wz_b  = wfc_b + WS_SZ;
    ushort_t* uz_b  = wz_b + WS_SZ;
    ushort_t* wr_b  = uz_b + WS_SZ;
    ushort_t* ur_b  = wr_b + WS_SZ;
    ushort_t* wg_b  = ur_b + WS_SZ;
    ushort_t* ug_b  = wg_b + WS_SZ;

    wcvt_kernel<<<(WQ_SZ + 7 * WS_SZ + 255) / 256, 256, 0, stream>>>(
        w_qkv, w_fc, w_z, u_z, w_r, u_r, w_g, u_g, wb);
    adjbits_kernel<<<(B_ * S_ * S_) / 256, 256, 0, stream>>>(adj, bits);
    ln_kernel<<<TOK, 256, 0, stream>>>(x, ln_g, ln_b, xn_b, x_b);

    gemm_bf16<<<dim3(12, 128), 256, 0, stream>>>(
        xn_b, wq_b, nullptr, nullptr, b_qkv, nullptr, nullptr,
        nullptr, qkv_b, (int)TOK, 3 * D_, D_, 0);

    attn_kernel<<<dim3(S_ / 64, B_ * H_), 256, 0, stream>>>(qkv_b, bits, attn_b);

    dim3 g256(4, 128);
    gemm_bf16<<<g256, 256, 0, stream>>>(
        attn_b, wfc_b, nullptr, nullptr, b_fc, nullptr, nullptr,
        nullptr, y_b, (int)TOK, D_, D_, 1);
    gemm_bf16<<<g256, 256, 0, stream>>>(
        y_b, wz_b, x_b, uz_b, b_z, nullptr, nullptr,
        z_f, nullptr, (int)TOK, D_, D_, 2);
    gemm_bf16<<<g256, 256, 0, stream>>>(
        y_b, wr_b, x_b, ur_b, nullptr, nullptr, x,
        nullptr, t_b, (int)TOK, D_, D_, 3);
    gemm_bf16<<<g256, 256, 0, stream>>>(
        y_b, wg_b, t_b, ug_b, nullptr, z_f, x,
        out, nullptr, (int)TOK, D_, D_, 4);
}

// Round 4
// 266.819 us; speedup vs baseline: 16.1409x; 1.0576x over previous
//
#include <hip/hip_runtime.h>
#include <hip/hip_bf16.h>
#include <math.h>

#define B_  4
#define S_  2048
#define D_  256
#define H_  8
#define HD_ 32
#define INV_SCALE 0.17677669529663687f   // 1/sqrt(32)

typedef short  bf16x8 __attribute__((ext_vector_type(8)));
typedef float  f32x4  __attribute__((ext_vector_type(4)));
typedef unsigned short ushort_t;
typedef unsigned int   uint_t;

__device__ __forceinline__ ushort_t f2b(float f) {
    union { float f; unsigned u; } v; v.f = f;
    unsigned r = (v.u + 0x7FFFu + ((v.u >> 16) & 1u)) >> 16;
    return (ushort_t)r;
}

// ---------------- reductions ----------------
__device__ __forceinline__ float wave_sum(float v) {
#pragma unroll
    for (int o = 32; o > 0; o >>= 1) v += __shfl_down(v, o, 64);
    return v;
}
__device__ __forceinline__ float block_sum256(float v, float* scr) {
    v = wave_sum(v);
    int lane = threadIdx.x & 63, wid = threadIdx.x >> 6;
    if (lane == 0) scr[wid] = v;
    __syncthreads();
    float r = scr[0] + scr[1] + scr[2] + scr[3];
    __syncthreads();
    return r;
}

// ---------------- merged prep: adj->bits | weight cvt | layernorm ----------------
#define WQ_SZ 196608   // 768*256
#define WS_SZ 65536    // 256*256
#define NB_ADJ 65536   // (4*2048*2048)/256
#define NB_WC  2560    // (WQ_SZ+7*WS_SZ)/256
#define NB_LN  8192
__global__ __launch_bounds__(256)
void prep_kernel(const int* __restrict__ adj, uint_t* __restrict__ bits,
                 const float* __restrict__ w0, const float* __restrict__ w1,
                 const float* __restrict__ w2, const float* __restrict__ w3,
                 const float* __restrict__ w4, const float* __restrict__ w5,
                 const float* __restrict__ w6, const float* __restrict__ w7,
                 ushort_t* __restrict__ wout,
                 const float* __restrict__ x, const float* __restrict__ g,
                 const float* __restrict__ bb, ushort_t* __restrict__ xn_b,
                 ushort_t* __restrict__ x_b) {
    __shared__ float scr[4];
    int blk = blockIdx.x, tid = threadIdx.x;
    if (blk < NB_ADJ) {
        size_t i = (size_t)blk * 256 + tid;
        unsigned long long m = __ballot(adj[i] != 0);
        int lane = tid & 63;
        size_t wbase = ((size_t)blk * 256 + (tid & ~63)) >> 5;
        if (lane == 0)  bits[wbase]     = (uint_t)m;
        if (lane == 32) bits[wbase + 1] = (uint_t)(m >> 32);
    } else if (blk < NB_ADJ + NB_WC) {
        int idx = (blk - NB_ADJ) * 256 + tid;
        const float* src; int off;
        if (idx < WQ_SZ) { src = w0; off = idx; }
        else {
            int j = idx - WQ_SZ, seg = j >> 16; off = j & (WS_SZ - 1);
            src = (seg == 0) ? w1 : (seg == 1) ? w2 : (seg == 2) ? w3 :
                  (seg == 3) ? w4 : (seg == 4) ? w5 : (seg == 5) ? w6 : w7;
        }
        wout[idx] = f2b(src[off]);
    } else {
        size_t base = (size_t)(blk - NB_ADJ - NB_WC) * D_;
        float v  = x[base + tid];
        float mu = block_sum256(v, scr) * (1.0f / D_);
        float d  = v - mu;
        float var = block_sum256(d * d, scr) * (1.0f / D_);
        float rstd = rsqrtf(var + 1e-5f);
        xn_b[base + tid] = f2b(d * rstd * g[tid] + bb[tid]);
        x_b[base + tid]  = f2b(v);
    }
}

// ---------------- bf16 MFMA GEMM, dual-A, fused epilogue ----------------
// epi: 0 plain->outb, 1 relu->outb, 5 q-col scale->outb,
//      4 final GRU: v+=pbuf; h=tanh(v); outf=(1-z)*resid+z*h
__global__ __launch_bounds__(256)
void gemm_bf16(const ushort_t* __restrict__ A1, const ushort_t* __restrict__ W1,
               const ushort_t* __restrict__ A2, const ushort_t* __restrict__ W2,
               const float* __restrict__ bias, const float* __restrict__ zbuf,
               const float* __restrict__ resid, const float* __restrict__ pbuf,
               float* __restrict__ outf, ushort_t* __restrict__ outb,
               int M, int N, int K, int epi) {
    __shared__ ushort_t As[64][40];
    __shared__ ushort_t Ws[64][40];
    int tid = threadIdx.x;
    int wave = tid >> 6, lane = tid & 63, l = lane & 15, quad = lane >> 4;
    int wm = wave >> 1, wn = wave & 1;
    int m0 = blockIdx.y * 64, n0 = blockIdx.x * 64;
    int srow = tid >> 2, skp = tid & 3;

    const ushort_t* Aps[2] = {A1, A2};
    const ushort_t* Wps[2] = {W1, W2};
    int ksteps = K >> 5;
    int nsteps = (A2 ? 2 : 1) * ksteps;

    f32x4 acc[2][2];
#pragma unroll
    for (int i = 0; i < 2; ++i)
#pragma unroll
        for (int j = 0; j < 2; ++j) acc[i][j] = (f32x4){0.f, 0.f, 0.f, 0.f};

    uint4 av = *(const uint4*)(Aps[0] + (size_t)(m0 + srow) * K + skp * 8);
    uint4 wv = *(const uint4*)(Wps[0] + (size_t)(n0 + srow) * K + skp * 8);

    for (int s = 0; s < nsteps; ++s) {
        uint4 ac = av, wc = wv;
        if (s + 1 < nsteps) {
            int s1 = s + 1;
            int p  = (s1 >= ksteps) ? 1 : 0;
            int kk = (s1 - p * ksteps) * 32;
            av = *(const uint4*)(Aps[p] + (size_t)(m0 + srow) * K + kk + skp * 8);
            wv = *(const uint4*)(Wps[p] + (size_t)(n0 + srow) * K + kk + skp * 8);
        }
        __syncthreads();
        *(uint4*)&As[srow][skp * 8] = ac;
        *(uint4*)&Ws[srow][skp * 8] = wc;
        __syncthreads();

        bf16x8 af[2], wf[2];
#pragma unroll
        for (int mt = 0; mt < 2; ++mt)
            af[mt] = *(const bf16x8*)&As[wm * 32 + mt * 16 + l][quad * 8];
#pragma unroll
        for (int nt = 0; nt < 2; ++nt)
            wf[nt] = *(const bf16x8*)&Ws[wn * 32 + nt * 16 + l][quad * 8];
#pragma unroll
        for (int mt = 0; mt < 2; ++mt)
#pragma unroll
            for (int nt = 0; nt < 2; ++nt)
                acc[mt][nt] = __builtin_amdgcn_mfma_f32_16x16x32_bf16(
                    af[mt], wf[nt], acc[mt][nt], 0, 0, 0);
    }

#pragma unroll
    for (int mt = 0; mt < 2; ++mt)
#pragma unroll
        for (int nt = 0; nt < 2; ++nt) {
            int col = n0 + wn * 32 + nt * 16 + l;
            float bv = bias ? bias[col] : 0.0f;
            float qs = 1.0f;
            if (epi == 5) qs = ((col % 96) < 32) ? INV_SCALE : 1.0f;
#pragma unroll
            for (int r = 0; r < 4; ++r) {
                int row = m0 + wm * 32 + mt * 16 + quad * 4 + r;
                float v = acc[mt][nt][r] + bv;
                size_t idx = (size_t)row * N + col;
                if (epi == 1) {
                    v = fmaxf(v, 0.0f);
                } else if (epi == 5) {
                    v *= qs;
                } else if (epi == 4) {
                    v += pbuf[idx];
                    float h = tanhf(v);
                    float z = zbuf[idx], rs = resid[idx];
                    v = (1.0f - z) * rs + z * h;
                }
                if (outf) outf[idx] = v;
                if (outb) outb[idx] = f2b(v);
            }
        }
}

// ---------------- fused gate GEMM: z, t=r*x, p=y@wg^T ----------------
__global__ __launch_bounds__(256)
void gemm_gate3(const ushort_t* __restrict__ Yb, const ushort_t* __restrict__ Xb,
                const ushort_t* __restrict__ Wz, const ushort_t* __restrict__ Uz,
                const ushort_t* __restrict__ Wr, const ushort_t* __restrict__ Ur,
                const ushort_t* __restrict__ Wg,
                const float* __restrict__ bz, const float* __restrict__ xf,
                float* __restrict__ z_f, ushort_t* __restrict__ t_b,
                float* __restrict__ p_f) {
    __shared__ ushort_t Sy[64][40], Sx[64][40];
    __shared__ ushort_t Swz[64][40], Suz[64][40], Swr[64][40], Sur[64][40], Swg[64][40];
    const int N = 256, K = 256;
    int tid = threadIdx.x;
    int wave = tid >> 6, lane = tid & 63, l = lane & 15, quad = lane >> 4;
    int wm = wave >> 1, wn = wave & 1;
    int m0 = blockIdx.y * 64, n0 = blockIdx.x * 64;
    int srow = tid >> 2, skp = tid & 3;

    f32x4 az[2][2], ar[2][2], ag[2][2];
#pragma unroll
    for (int i = 0; i < 2; ++i)
#pragma unroll
        for (int j = 0; j < 2; ++j) {
            az[i][j] = (f32x4){0.f, 0.f, 0.f, 0.f};
            ar[i][j] = (f32x4){0.f, 0.f, 0.f, 0.f};
            ag[i][j] = (f32x4){0.f, 0.f, 0.f, 0.f};
        }

    size_t aoff = (size_t)(m0 + srow) * K + skp * 8;
    size_t woff = (size_t)(n0 + srow) * K + skp * 8;
    uint4 py  = *(const uint4*)(Yb + aoff);
    uint4 px  = *(const uint4*)(Xb + aoff);
    uint4 pwz = *(const uint4*)(Wz + woff);
    uint4 puz = *(const uint4*)(Uz + woff);
    uint4 pwr = *(const uint4*)(Wr + woff);
    uint4 pur = *(const uint4*)(Ur + woff);
    uint4 pwg = *(const uint4*)(Wg + woff);

    for (int s = 0; s < 8; ++s) {
        uint4 cy = py, cx = px, cwz = pwz, cuz = puz, cwr = pwr, cur = pur, cwg = pwg;
        if (s < 7) {
            int kk = (s + 1) * 32;
            py  = *(const uint4*)(Yb + aoff + kk);
            px  = *(const uint4*)(Xb + aoff + kk);
            pwz = *(const uint4*)(Wz + woff + kk);
            puz = *(const uint4*)(Uz + woff + kk);
            pwr = *(const uint4*)(Wr + woff + kk);
            pur = *(const uint4*)(Ur + woff + kk);
            pwg = *(const uint4*)(Wg + woff + kk);
        }
        __syncthreads();
        *(uint4*)&Sy[srow][skp * 8]  = cy;
        *(uint4*)&Sx[srow][skp * 8]  = cx;
        *(uint4*)&Swz[srow][skp * 8] = cwz;
        *(uint4*)&Suz[srow][skp * 8] = cuz;
        *(uint4*)&Swr[srow][skp * 8] = cwr;
        *(uint4*)&Sur[srow][skp * 8] = cur;
        *(uint4*)&Swg[srow][skp * 8] = cwg;
        __syncthreads();

        bf16x8 fy[2], fx[2];
#pragma unroll
        for (int mt = 0; mt < 2; ++mt) {
            fy[mt] = *(const bf16x8*)&Sy[wm * 32 + mt * 16 + l][quad * 8];
            fx[mt] = *(const bf16x8*)&Sx[wm * 32 + mt * 16 + l][quad * 8];
        }
#pragma unroll
        for (int nt = 0; nt < 2; ++nt) {
            int wrow = wn * 32 + nt * 16 + l;
            bf16x8 fwz = *(const bf16x8*)&Swz[wrow][quad * 8];
            bf16x8 fuz = *(const bf16x8*)&Suz[wrow][quad * 8];
            bf16x8 fwr = *(const bf16x8*)&Swr[wrow][quad * 8];
            bf16x8 fur = *(const bf16x8*)&Sur[wrow][quad * 8];
            bf16x8 fwg = *(const bf16x8*)&Swg[wrow][quad * 8];
#pragma unroll
            for (int mt = 0; mt < 2; ++mt) {
                az[mt][nt] = __builtin_amdgcn_mfma_f32_16x16x32_bf16(fy[mt], fwz, az[mt][nt], 0, 0, 0);
                az[mt][nt] = __builtin_amdgcn_mfma_f32_16x16x32_bf16(fx[mt], fuz, az[mt][nt], 0, 0, 0);
                ar[mt][nt] = __builtin_amdgcn_mfma_f32_16x16x32_bf16(fy[mt], fwr, ar[mt][nt], 0, 0, 0);
                ar[mt][nt] = __builtin_amdgcn_mfma_f32_16x16x32_bf16(fx[mt], fur, ar[mt][nt], 0, 0, 0);
                ag[mt][nt] = __builtin_amdgcn_mfma_f32_16x16x32_bf16(fy[mt], fwg, ag[mt][nt], 0, 0, 0);
            }
        }
    }

#pragma unroll
    for (int mt = 0; mt < 2; ++mt)
#pragma unroll
        for (int nt = 0; nt < 2; ++nt) {
            int col = n0 + wn * 32 + nt * 16 + l;
            float bzv = bz[col];
#pragma unroll
            for (int r = 0; r < 4; ++r) {
                int row = m0 + wm * 32 + mt * 16 + quad * 4 + r;
                size_t idx = (size_t)row * N + col;
                float zv = 1.0f / (1.0f + __expf(-(az[mt][nt][r] + bzv)));
                z_f[idx] = zv;
                float rv = 1.0f / (1.0f + __expf(-ar[mt][nt][r]));
                t_b[idx] = f2b(rv * xf[idx]);
                p_f[idx] = ag[mt][nt][r];
            }
        }
}

// ---------------- MFMA flash attention (S^T layout) ----------------
// grid (S/64, B*H), block 256. Q pre-scaled by 1/sqrt(32) in QKV epilogue.
// S^T = mfma(K,Q): lane l = query, regs = 4 contiguous keys -> packed b64 P store.
// Vt staged with d-block XOR swizzle to break the 8-way transpose-scatter conflict.
__global__ __launch_bounds__(256)
void attn_kernel(const ushort_t* __restrict__ qkvb, const uint_t* __restrict__ abits,
                 ushort_t* __restrict__ attn_b) {
    __shared__ ushort_t Ks[64][40];   // [key][d]
    __shared__ ushort_t Vt[32][72];   // [d][key], col-block ^= (d>>3)&3
    __shared__ ushort_t Ps[64][72];   // [q][key], wave-private 16-row bands
    __shared__ uint_t  ab_sh[64][2];

    int tid = threadIdx.x;
    int wave = tid >> 6, lane = tid & 63, l = lane & 15, quad = lane >> 4;
    int q0 = blockIdx.x * 64;
    int n  = blockIdx.y;
    int b = n >> 3, h = n & 7;
    int bp = n & 3, hp = n >> 2;

    const ushort_t* base = qkvb + (size_t)b * S_ * 768 + h * 96;
    int myq = wave * 16 + l;

    // Q as B-frag: B[k=quad*8+j][n=l] = Q[q0+myq][quad*8+j]
    bf16x8 qf = *(const bf16x8*)(base + (size_t)(q0 + myq) * 768 + quad * 8);

    f32x4 oacc[2];
    oacc[0] = (f32x4){0.f, 0.f, 0.f, 0.f};
    oacc[1] = (f32x4){0.f, 0.f, 0.f, 0.f};
    float lsum = 0.0f;

    int skey = tid >> 2, spart = tid & 3;
    int sblk = skey >> 3, scol = skey & 7;

    uint4 kv = *(const uint4*)(base + (size_t)skey * 768 + 32 + spart * 8);
    uint4 vv = *(const uint4*)(base + (size_t)skey * 768 + 64 + spart * 8);
    uint_t aw = 0;
    if (tid < 128)
        aw = abits[((size_t)b * S_ + q0 + (tid >> 1)) * 64 + (tid & 1)];

    for (int k0 = 0; k0 < S_; k0 += 64) {
        uint4 kc = kv, vc = vv; uint_t ac = aw;
        if (k0 + 64 < S_) {
            kv = *(const uint4*)(base + (size_t)(k0 + 64 + skey) * 768 + 32 + spart * 8);
            vv = *(const uint4*)(base + (size_t)(k0 + 64 + skey) * 768 + 64 + spart * 8);
            if (tid < 128)
                aw = abits[((size_t)b * S_ + q0 + (tid >> 1)) * 64 + ((k0 + 64) >> 5) + (tid & 1)];
        }
        __syncthreads();
        *(uint4*)&Ks[skey][spart * 8] = kc;
        {
            const ushort_t* vs = (const ushort_t*)&vc;
            int cb = ((sblk ^ spart) << 3) | scol;   // (d>>3)&3 == spart
#pragma unroll
            for (int i = 0; i < 8; ++i) Vt[spart * 8 + i][cb] = vs[i];
        }
        if (tid < 128) ab_sh[tid >> 1][tid & 1] = ac;
        __syncthreads();

        uint_t aw0 = ab_sh[myq][0], aw1 = ab_sh[myq][1];

        // S^T tiles: keys t4*16+quad*4+r for query myq
#pragma unroll
        for (int t4 = 0; t4 < 4; ++t4) {
            bf16x8 kf = *(const bf16x8*)&Ks[t4 * 16 + l][quad * 8];
            f32x4 z = (f32x4){0.f, 0.f, 0.f, 0.f};
            f32x4 sc = __builtin_amdgcn_mfma_f32_16x16x32_bf16(kf, qf, z, 0, 0, 0);
            uint_t w = (t4 & 2) ? aw1 : aw0;
            uint_t wq = w >> ((t4 & 1) * 16 + quad * 4);
            float p[4];
#pragma unroll
            for (int r = 0; r < 4; ++r) {
                uint_t mneg = 0u - ((wq >> r) & 1u);
                float e = __expf(sc[r]);
                p[r] = __uint_as_float(__float_as_uint(e) & mneg);
                lsum += p[r];
            }
            union { __hip_bfloat162 b2[2]; uint2 u2; } pk;
            pk.b2[0] = __float22bfloat162_rn(make_float2(p[0], p[1]));
            pk.b2[1] = __float22bfloat162_rn(make_float2(p[2], p[3]));
            *(uint2*)&Ps[myq][t4 * 16 + quad * 4] = pk.u2;
        }

        // PV^T: D[d][q] += V^T[d][k] * P^T[k][q]  (wave-private Ps rows)
#pragma unroll
        for (int ks = 0; ks < 2; ++ks) {
            bf16x8 pf = *(const bf16x8*)&Ps[wave * 16 + l][ks * 32 + quad * 8];
#pragma unroll
            for (int mt = 0; mt < 2; ++mt) {
                int dblk = (mt * 2 + (l >> 3)) & 3;
                bf16x8 vf = *(const bf16x8*)&Vt[mt * 16 + l][(((ks * 4 + quad) ^ dblk) & 7) * 8];
                oacc[mt] = __builtin_amdgcn_mfma_f32_16x16x32_bf16(vf, pf, oacc[mt], 0, 0, 0);
            }
        }
    }

    // lsum: reduce across the 4 quads (lanes l, l+16, l+32, l+48)
    lsum += __shfl_xor(lsum, 16, 64);
    lsum += __shfl_xor(lsum, 32, 64);
    float linv = 1.0f / lsum;

    size_t orow = ((size_t)(bp * S_ + q0 + myq)) * D_ + hp * HD_;
#pragma unroll
    for (int mt = 0; mt < 2; ++mt)
#pragma unroll
        for (int r = 0; r < 4; ++r)
            attn_b[orow + mt * 16 + quad * 4 + r] = f2b(oacc[mt][r] * linv);
}

// ---------------- launch ----------------
extern "C" void kernel_launch(void* const* d_in, const int* in_sizes, int n_in,
                              void* d_out, int out_size, void* d_ws, size_t ws_size,
                              hipStream_t stream) {
    const float* x     = (const float*)d_in[0];
    const int*   adj   = (const int*)d_in[1];
    const float* w_qkv = (const float*)d_in[2];
    const float* b_qkv = (const float*)d_in[3];
    const float* ln_g  = (const float*)d_in[4];
    const float* ln_b  = (const float*)d_in[5];
    const float* w_fc  = (const float*)d_in[6];
    const float* b_fc  = (const float*)d_in[7];
    const float* w_z   = (const float*)d_in[8];
    const float* b_z   = (const float*)d_in[9];
    const float* u_z   = (const float*)d_in[10];
    const float* w_r   = (const float*)d_in[11];
    const float* u_r   = (const float*)d_in[12];
    const float* w_g   = (const float*)d_in[13];
    const float* u_g   = (const float*)d_in[14];
    float* out = (float*)d_out;

    const size_t TOK  = (size_t)B_ * S_;       // 8192
    const size_t TOKD = TOK * D_;              // 2,097,152
    ushort_t* xn_b   = (ushort_t*)d_ws;
    ushort_t* x_b    = xn_b + TOKD;
    ushort_t* qkv_b  = x_b + TOKD;             // 6,291,456 elems
    float*    z_f    = (float*)qkv_b;          // alias: qkv dead after attn
    ushort_t* attn_b = qkv_b + TOK * 768;
    ushort_t* y_b    = attn_b + TOKD;
    ushort_t* t_b    = y_b + TOKD;
    ushort_t* wb     = t_b + TOKD;             // 655,360 elems
    float*    p_f    = (float*)(wb + WQ_SZ + 7 * WS_SZ);
    uint_t*   bits   = (uint_t*)(p_f + TOKD);

    ushort_t* wq_b  = wb;
    ushort_t* wfc_b = wb + WQ_SZ;
    ushort_t* wz_b  = wfc_b + WS_SZ;
    ushort_t* uz_b  = wz_b + WS_SZ;
    ushort_t* wr_b  = uz_b + WS_SZ;
    ushort_t* ur_b  = wr_b + WS_SZ;
    ushort_t* wg_b  = ur_b + WS_SZ;
    ushort_t* ug_b  = wg_b + WS_SZ;

    prep_kernel<<<NB_ADJ + NB_WC + NB_LN, 256, 0, stream>>>(
        adj, bits, w_qkv, w_fc, w_z, u_z, w_r, u_r, w_g, u_g, wb,
        x, ln_g, ln_b, xn_b, x_b);

    // QKV projection, q-columns pre-scaled by 1/sqrt(32)
    gemm_bf16<<<dim3(12, 128), 256, 0, stream>>>(
        xn_b, wq_b, nullptr, nullptr, b_qkv, nullptr, nullptr, nullptr,
        nullptr, qkv_b, (int)TOK, 3 * D_, D_, 5);

    attn_kernel<<<dim3(S_ / 64, B_ * H_), 256, 0, stream>>>(qkv_b, bits, attn_b);

    dim3 g256(4, 128);
    // y = relu(attn @ w_fc^T + b_fc)
    gemm_bf16<<<g256, 256, 0, stream>>>(
        attn_b, wfc_b, nullptr, nullptr, b_fc, nullptr, nullptr, nullptr,
        nullptr, y_b, (int)TOK, D_, D_, 1);
    // z, t=r*x, p=y@w_g^T in one fused kernel
    gemm_gate3<<<g256, 256, 0, stream>>>(
        y_b, x_b, wz_b, uz_b, wr_b, ur_b, wg_b, b_z, x, z_f, t_b, p_f);
    // out = (1-z)*x + z*tanh(p + t @ u_g^T)
    gemm_bf16<<<g256, 256, 0, stream>>>(
        t_b, ug_b, nullptr, nullptr, nullptr, z_f, x, p_f,
        out, nullptr, (int)TOK, D_, D_, 4);
}